// Round 1
// baseline (979.629 us; speedup 1.0000x reference)
//
#include <hip/hip_runtime.h>

// ---------------------------------------------------------------------------
// AttDual: features ->(Linear+LN+GELU) K ->(x2) V,Q ; q_max = Q[argmax(c)] ;
// A = softmax(Q q_max^T / 32, axis=0) ; B = A^T V ; C = <B, head_w> + head_b
// All heavy GEMMs in bf16 MFMA (16x16x32), fp32 accumulate. fp32 in/out.
// ---------------------------------------------------------------------------

typedef unsigned short u16;
typedef __attribute__((ext_vector_type(8))) short     bf16x8;
typedef __attribute__((ext_vector_type(8))) unsigned short u16x8;
typedef __attribute__((ext_vector_type(4))) float     f32x4;

#define DDIM  1024
#define NROWS 50000
#define MP    50048      // 391 * 128, padded rows (zeros)
#define NCLS  7

__device__ __forceinline__ u16 f2bf(float f) {          // RNE fp32 -> bf16
  unsigned u = __float_as_uint(f);
  u = (u + 0x7FFFu + ((u >> 16) & 1u)) >> 16;
  return (u16)u;
}
__device__ __forceinline__ float bf2f(u16 h) {
  return __uint_as_float(((unsigned)h) << 16);
}

__device__ __forceinline__ void load16_lds(const u16* g, u16* l) {
  __builtin_amdgcn_global_load_lds(
      (const __attribute__((address_space(1))) unsigned int*)(const void*)g,
      (__attribute__((address_space(3))) unsigned int*)(void*)l, 16, 0, 0);
}

// ------------------------- fp32 -> bf16 convert (+row zero-pad) ------------
__global__ __launch_bounds__(256) void k_convert(const float* __restrict__ src,
                                                 u16* __restrict__ dst,
                                                 int rows_total, int rows_valid) {
  const size_t total = (size_t)rows_total * DDIM / 8;
  const size_t stride = (size_t)gridDim.x * blockDim.x;
  for (size_t i = (size_t)blockIdx.x * blockDim.x + threadIdx.x; i < total; i += stride) {
    const size_t e = i * 8;
    const int row = (int)(e >> 10);     // DDIM = 1024
    u16x8 o = {0, 0, 0, 0, 0, 0, 0, 0};
    if (row < rows_valid) {
      const float4* p = (const float4*)(src + e);
      float4 f0 = p[0], f1 = p[1];
      o[0] = f2bf(f0.x); o[1] = f2bf(f0.y); o[2] = f2bf(f0.z); o[3] = f2bf(f0.w);
      o[4] = f2bf(f1.x); o[5] = f2bf(f1.y); o[6] = f2bf(f1.z); o[7] = f2bf(f1.w);
    }
    *(u16x8*)(dst + e) = o;
  }
}

// ------------------------- bf16 GEMM: C[m,n] = sum_k A[m,k]*B[n,k] ---------
// A [MP,1024] bf16, B [1024,1024] bf16 (row n = weights of output col n).
// 128x128 tile, BK=32, 4 waves (each 64x64 = 4x4 fragments of 16x16x32).
__global__ __launch_bounds__(256) void k_gemm_bt(const u16* __restrict__ A,
                                                 const u16* __restrict__ B,
                                                 u16* __restrict__ C) {
  __shared__ __align__(16) u16 As[128 * 32];
  __shared__ __align__(16) u16 Bs[128 * 32];
  const int tid  = threadIdx.x;
  const int lane = tid & 63;
  const int m0 = blockIdx.y * 128;
  const int n0 = blockIdx.x * 128;
  const int wid = tid >> 6;
  const int wr = (wid >> 1) * 64;
  const int wc = (wid & 1) * 64;

  // staging: chunk c in [0,1024) covers As[c*8 .. c*8+8) = tile row c>>2, cols (c&3)*8..
  const int rA = tid >> 2;              // 0..63
  const int cA = (tid & 3) * 8;
  const u16* Ap0 = A + (size_t)(m0 + rA) * DDIM + cA;
  const u16* Ap1 = Ap0 + (size_t)64 * DDIM;
  const u16* Bp0 = B + (size_t)(n0 + rA) * DDIM + cA;
  const u16* Bp1 = Bp0 + (size_t)64 * DDIM;
  const int wbase = wid * 64;           // wave-uniform LDS chunk base
  u16* AsD0 = &As[(wbase)        * 8];
  u16* AsD1 = &As[(wbase + 256)  * 8];
  u16* BsD0 = &Bs[(wbase)        * 8];
  u16* BsD1 = &Bs[(wbase + 256)  * 8];

  f32x4 acc[4][4] = {};
  const int fr = lane & 15;
  const int kh = (lane >> 4) * 8;

  for (int k0 = 0; k0 < DDIM; k0 += 32) {
    __syncthreads();                     // protect LDS from previous iter reads
    load16_lds(Ap0 + k0, AsD0);
    load16_lds(Ap1 + k0, AsD1);
    load16_lds(Bp0 + k0, BsD0);
    load16_lds(Bp1 + k0, BsD1);
    __syncthreads();                     // drains vmcnt (compiler-inserted)
    bf16x8 a[4], b[4];
#pragma unroll
    for (int i = 0; i < 4; ++i) a[i] = *(const bf16x8*)&As[(wr + i * 16 + fr) * 32 + kh];
#pragma unroll
    for (int j = 0; j < 4; ++j) b[j] = *(const bf16x8*)&Bs[(wc + j * 16 + fr) * 32 + kh];
#pragma unroll
    for (int i = 0; i < 4; ++i)
#pragma unroll
      for (int j = 0; j < 4; ++j)
        acc[i][j] = __builtin_amdgcn_mfma_f32_16x16x32_bf16(a[i], b[j], acc[i][j], 0, 0, 0);
  }

  // C/D layout: col = lane&15, row = (lane>>4)*4 + reg   [m89-verified]
  const int orow = (lane >> 4) * 4;
  const int ocol = lane & 15;
#pragma unroll
  for (int i = 0; i < 4; ++i)
#pragma unroll
    for (int j = 0; j < 4; ++j) {
      const size_t base = (size_t)(m0 + wr + i * 16 + orow) * DDIM + (n0 + wc + j * 16 + ocol);
#pragma unroll
      for (int r = 0; r < 4; ++r)
        C[base + (size_t)r * DDIM] = f2bf(acc[i][j][r]);
    }
}

// ------------------------- bias + LayerNorm + exact GELU -------------------
// wave per row; lane handles 16 contiguous cols. Pad rows -> zeros.
__global__ __launch_bounds__(256) void k_ln_gelu(const u16* __restrict__ h,
                                                 const float* __restrict__ bias,
                                                 const float* __restrict__ g,
                                                 const float* __restrict__ beta,
                                                 u16* __restrict__ out) {
  const int lane = threadIdx.x & 63;
  const int row = blockIdx.x * 4 + (threadIdx.x >> 6);
  const int c0 = lane * 16;
  u16x8* op = (u16x8*)(out + (size_t)row * DDIM + c0);
  if (row >= NROWS) {
    u16x8 z = {0, 0, 0, 0, 0, 0, 0, 0};
    op[0] = z; op[1] = z;
    return;
  }
  const u16x8* hp = (const u16x8*)(h + (size_t)row * DDIM + c0);
  u16x8 h0 = hp[0], h1 = hp[1];
  const float4* bp = (const float4*)(bias + c0);
  float4 b0 = bp[0], b1 = bp[1], b2 = bp[2], b3 = bp[3];
  float bb[16] = {b0.x, b0.y, b0.z, b0.w, b1.x, b1.y, b1.z, b1.w,
                  b2.x, b2.y, b2.z, b2.w, b3.x, b3.y, b3.z, b3.w};
  float v[16];
#pragma unroll
  for (int e = 0; e < 8; ++e) {
    v[e]     = bf2f(h0[e]) + bb[e];
    v[e + 8] = bf2f(h1[e]) + bb[e + 8];
  }
  float s1 = 0.f, s2 = 0.f;
#pragma unroll
  for (int e = 0; e < 16; ++e) { s1 += v[e]; s2 += v[e] * v[e]; }
#pragma unroll
  for (int m = 1; m < 64; m <<= 1) {
    s1 += __shfl_xor(s1, m, 64);
    s2 += __shfl_xor(s2, m, 64);
  }
  const float mu = s1 * (1.0f / 1024.0f);
  const float var = s2 * (1.0f / 1024.0f) - mu * mu;
  const float rs = rsqrtf(var + 1e-5f);
  const float4* gp = (const float4*)(g + c0);
  float4 g0 = gp[0], g1 = gp[1], g2 = gp[2], g3 = gp[3];
  float gg[16] = {g0.x, g0.y, g0.z, g0.w, g1.x, g1.y, g1.z, g1.w,
                  g2.x, g2.y, g2.z, g2.w, g3.x, g3.y, g3.z, g3.w};
  const float4* ep = (const float4*)(beta + c0);
  float4 e0 = ep[0], e1 = ep[1], e2 = ep[2], e3 = ep[3];
  float bt[16] = {e0.x, e0.y, e0.z, e0.w, e1.x, e1.y, e1.z, e1.w,
                  e2.x, e2.y, e2.z, e2.w, e3.x, e3.y, e3.z, e3.w};
  u16x8 o0, o1;
#pragma unroll
  for (int e = 0; e < 16; ++e) {
    const float x = (v[e] - mu) * rs * gg[e] + bt[e];
    const float y = 0.5f * x * (1.0f + erff(x * 0.70710678118654752f));
    if (e < 8) o0[e] = f2bf(y); else o1[e - 8] = f2bf(y);
  }
  op[0] = o0; op[1] = o1;
}

// ------------------------- argmax over axis 0 per class (first-index) ------
__global__ __launch_bounds__(256) void k_argmax(const float* __restrict__ c,
                                                int* __restrict__ top) {
  __shared__ float sv[256 * NCLS];
  __shared__ int   si[256 * NCLS];
  const int tid = threadIdx.x;
  float bv[NCLS]; int bi[NCLS];
#pragma unroll
  for (int j = 0; j < NCLS; ++j) { bv[j] = -3.4e38f; bi[j] = 0; }
  for (int n = tid; n < NROWS; n += 256) {
#pragma unroll
    for (int j = 0; j < NCLS; ++j) {
      const float v = c[(size_t)n * NCLS + j];
      if (v > bv[j]) { bv[j] = v; bi[j] = n; }   // strict > keeps first idx
    }
  }
#pragma unroll
  for (int j = 0; j < NCLS; ++j) { sv[tid * NCLS + j] = bv[j]; si[tid * NCLS + j] = bi[j]; }
  __syncthreads();
  for (int s = 128; s > 0; s >>= 1) {
    if (tid < s) {
#pragma unroll
      for (int j = 0; j < NCLS; ++j) {
        const float v2 = sv[(tid + s) * NCLS + j]; const int i2 = si[(tid + s) * NCLS + j];
        const float v1 = sv[tid * NCLS + j];       const int i1 = si[tid * NCLS + j];
        if (v2 > v1 || (v2 == v1 && i2 < i1)) { sv[tid * NCLS + j] = v2; si[tid * NCLS + j] = i2; }
      }
    }
    __syncthreads();
  }
  if (tid < NCLS) top[tid] = si[tid];
}

// ------------------------- logits[n,j] = <Q[n], Q[top[j]]> / 32 ------------
__global__ __launch_bounds__(256) void k_logits(const u16* __restrict__ Q,
                                                const int* __restrict__ top,
                                                float* __restrict__ logits) {
  __shared__ __align__(16) u16 qm[NCLS * DDIM];
  const int tid = threadIdx.x;
  for (int i = tid; i < NCLS * (DDIM / 8); i += 256) {
    const int j = i >> 7;        // DDIM/8 = 128
    const int ch = i & 127;
    *(u16x8*)&qm[j * DDIM + ch * 8] = *(const u16x8*)&Q[(size_t)top[j] * DDIM + ch * 8];
  }
  __syncthreads();
  const int lane = tid & 63;
  const int n = blockIdx.x * 4 + (tid >> 6);
  if (n >= NROWS) return;
  const u16x8* qp = (const u16x8*)(Q + (size_t)n * DDIM + lane * 16);
  u16x8 q0 = qp[0], q1 = qp[1];
  float qf[16];
#pragma unroll
  for (int e = 0; e < 8; ++e) { qf[e] = bf2f(q0[e]); qf[e + 8] = bf2f(q1[e]); }
  float acc[NCLS];
#pragma unroll
  for (int j = 0; j < NCLS; ++j) acc[j] = 0.f;
#pragma unroll
  for (int j = 0; j < NCLS; ++j) {
    const u16x8* mp = (const u16x8*)&qm[j * DDIM + lane * 16];
    u16x8 m0 = mp[0], m1 = mp[1];
#pragma unroll
    for (int e = 0; e < 8; ++e) acc[j] += qf[e] * bf2f(m0[e]) + qf[e + 8] * bf2f(m1[e]);
  }
#pragma unroll
  for (int j = 0; j < NCLS; ++j) {
    float v = acc[j];
#pragma unroll
    for (int m = 1; m < 64; m <<= 1) v += __shfl_xor(v, m, 64);
    if (lane == 0) logits[(size_t)n * NCLS + j] = v * 0.03125f;   // 1/sqrt(1024)
  }
}

// ------------------------- softmax over axis 0: 2-stage max & sum ----------
__global__ __launch_bounds__(256) void k_cmax_part(const float* __restrict__ logits,
                                                   float* __restrict__ pout) {
  __shared__ float sm[256 * NCLS];
  const int tid = threadIdx.x;
  float m[NCLS];
#pragma unroll
  for (int j = 0; j < NCLS; ++j) m[j] = -3.4e38f;
  const size_t stride = (size_t)gridDim.x * 256;
  for (size_t n = (size_t)blockIdx.x * 256 + tid; n < NROWS; n += stride)
#pragma unroll
    for (int j = 0; j < NCLS; ++j) m[j] = fmaxf(m[j], logits[n * NCLS + j]);
#pragma unroll
  for (int j = 0; j < NCLS; ++j) sm[tid * NCLS + j] = m[j];
  __syncthreads();
  for (int s = 128; s > 0; s >>= 1) {
    if (tid < s)
#pragma unroll
      for (int j = 0; j < NCLS; ++j)
        sm[tid * NCLS + j] = fmaxf(sm[tid * NCLS + j], sm[(tid + s) * NCLS + j]);
    __syncthreads();
  }
  if (tid < NCLS) pout[blockIdx.x * NCLS + tid] = sm[tid];
}

__global__ void k_cmax_fin(const float* __restrict__ pin, float* __restrict__ M, int nparts) {
  const int tid = threadIdx.x;
  if (tid < NCLS) {
    float m = -3.4e38f;
    for (int b = 0; b < nparts; ++b) m = fmaxf(m, pin[b * NCLS + tid]);
    M[tid] = m;
  }
}

__global__ __launch_bounds__(256) void k_csum_part(const float* __restrict__ logits,
                                                   const float* __restrict__ M,
                                                   float* __restrict__ pout) {
  __shared__ float sm[256 * NCLS];
  __shared__ float sM[NCLS];
  const int tid = threadIdx.x;
  if (tid < NCLS) sM[tid] = M[tid];
  __syncthreads();
  float s[NCLS];
#pragma unroll
  for (int j = 0; j < NCLS; ++j) s[j] = 0.f;
  const size_t stride = (size_t)gridDim.x * 256;
  for (size_t n = (size_t)blockIdx.x * 256 + tid; n < NROWS; n += stride)
#pragma unroll
    for (int j = 0; j < NCLS; ++j) s[j] += expf(logits[n * NCLS + j] - sM[j]);
#pragma unroll
  for (int j = 0; j < NCLS; ++j) sm[tid * NCLS + j] = s[j];
  __syncthreads();
  for (int st = 128; st > 0; st >>= 1) {
    if (tid < st)
#pragma unroll
      for (int j = 0; j < NCLS; ++j) sm[tid * NCLS + j] += sm[(tid + st) * NCLS + j];
    __syncthreads();
  }
  if (tid < NCLS) pout[blockIdx.x * NCLS + tid] = sm[tid];
}

__global__ void k_csum_fin(const float* __restrict__ pin, float* __restrict__ S, int nparts) {
  const int tid = threadIdx.x;
  if (tid < NCLS) {
    float s = 0.f;
    for (int b = 0; b < nparts; ++b) s += pin[b * NCLS + tid];
    S[tid] = s;
  }
}

__global__ __launch_bounds__(256) void k_writeA(const float* __restrict__ logits,
                                                const float* __restrict__ M,
                                                const float* __restrict__ S,
                                                float* __restrict__ Aout) {
  __shared__ float sM[NCLS], sR[NCLS];
  if (threadIdx.x < NCLS) { sM[threadIdx.x] = M[threadIdx.x]; sR[threadIdx.x] = 1.0f / S[threadIdx.x]; }
  __syncthreads();
  const size_t total = (size_t)NROWS * NCLS;
  const size_t stride = (size_t)gridDim.x * blockDim.x;
  for (size_t i = (size_t)blockIdx.x * blockDim.x + threadIdx.x; i < total; i += stride) {
    const int j = (int)(i % NCLS);
    Aout[i] = expf(logits[i] - sM[j]) * sR[j];
  }
}

// ------------------------- B = A^T V : partial over row chunks -------------
__global__ __launch_bounds__(256) void k_bpart(const float* __restrict__ Aout,
                                               const u16* __restrict__ V,
                                               float* __restrict__ Pb) {
  const int col = blockIdx.x * 256 + threadIdx.x;          // 0..1023
  const int n0 = blockIdx.y * 782;
  const int n1 = min(n0 + 782, NROWS);
  __shared__ float sA[256 * NCLS];
  float acc[NCLS] = {0.f, 0.f, 0.f, 0.f, 0.f, 0.f, 0.f};
  for (int base = n0; base < n1; base += 256) {
    const int cnt = min(256, n1 - base);
    __syncthreads();
    for (int q = threadIdx.x; q < cnt * NCLS; q += 256) sA[q] = Aout[(size_t)base * NCLS + q];
    __syncthreads();
    for (int r = 0; r < cnt; ++r) {
      const float v = bf2f(V[(size_t)(base + r) * DDIM + col]);
#pragma unroll
      for (int j = 0; j < NCLS; ++j) acc[j] += sA[r * NCLS + j] * v;
    }
  }
#pragma unroll
  for (int j = 0; j < NCLS; ++j)
    Pb[((size_t)blockIdx.y * NCLS + j) * DDIM + col] = acc[j];
}

__global__ void k_bred(const float* __restrict__ Pb, float* __restrict__ Bout) {
  const int idx = blockIdx.x * 256 + threadIdx.x;
  if (idx >= NCLS * DDIM) return;
  float s = 0.f;
  for (int nb = 0; nb < 64; ++nb) s += Pb[(size_t)nb * NCLS * DDIM + idx];
  Bout[idx] = s;
}

// ------------------------- C[o] = sum_{i,k} B[i,k] head_w[o,i,k] + head_b --
__global__ __launch_bounds__(256) void k_head(const float* __restrict__ Bmat,
                                              const float* __restrict__ hw,
                                              const float* __restrict__ hb,
                                              float* __restrict__ Cout) {
  __shared__ float red[NCLS][256];
  const int tid = threadIdx.x;
  float p[NCLS] = {0.f, 0.f, 0.f, 0.f, 0.f, 0.f, 0.f};
  for (int idx = tid; idx < NCLS * DDIM; idx += 256) {
    const float bv = Bmat[idx];
#pragma unroll
    for (int o = 0; o < NCLS; ++o) p[o] += bv * hw[o * NCLS * DDIM + idx];
  }
#pragma unroll
  for (int o = 0; o < NCLS; ++o) red[o][tid] = p[o];
  __syncthreads();
  for (int s = 128; s > 0; s >>= 1) {
    if (tid < s)
#pragma unroll
      for (int o = 0; o < NCLS; ++o) red[o][tid] += red[o][tid + s];
    __syncthreads();
  }
  if (tid < NCLS) Cout[tid] = red[tid][0] + hb[tid];
}

// ---------------------------------------------------------------------------
extern "C" void kernel_launch(void* const* d_in, const int* in_sizes, int n_in,
                              void* d_out, int out_size, void* d_ws, size_t ws_size,
                              hipStream_t stream) {
  const float* features   = (const float*)d_in[0];
  const float* c_in       = (const float*)d_in[1];
  const float* key_w      = (const float*)d_in[2];
  const float* key_b      = (const float*)d_in[3];
  const float* key_g      = (const float*)d_in[4];
  const float* key_beta   = (const float*)d_in[5];
  const float* query_w    = (const float*)d_in[6];
  const float* query_b    = (const float*)d_in[7];
  const float* query_g    = (const float*)d_in[8];
  const float* query_beta = (const float*)d_in[9];
  const float* value_w    = (const float*)d_in[10];
  const float* value_b    = (const float*)d_in[11];
  const float* value_g    = (const float*)d_in[12];
  const float* value_beta = (const float*)d_in[13];
  const float* head_w     = (const float*)d_in[14];
  const float* head_b     = (const float*)d_in[15];

  char* ws = (char*)d_ws;
  const size_t SZB = (size_t)MP * DDIM * sizeof(u16);        // 102.5 MB
  u16* Xb = (u16*)(ws);                 // features bf16; reused as V later
  u16* Hb = (u16*)(ws + SZB);           // GEMM output (pre-LN), reused x3
  u16* Kb = (u16*)(ws + 2 * SZB);
  u16* Qb = (u16*)(ws + 3 * SZB);
  u16* Wk = (u16*)(ws + 4 * SZB);
  u16* Wq = Wk + (size_t)DDIM * DDIM;
  u16* Wv = Wq + (size_t)DDIM * DDIM;
  float* logits = (float*)(Wv + (size_t)DDIM * DDIM);
  int*   top    = (int*)(logits + (size_t)NROWS * NCLS);
  float* Mmax   = (float*)(top + 16);
  float* Ssum   = Mmax + 8;
  float* Pmax   = Ssum + 8;                   // 128*7
  float* Psum   = Pmax + 128 * NCLS;
  float* Pb     = Psum + 128 * NCLS;          // 64*7*1024
  u16*   Vb     = Xb;

  float* Cout = (float*)d_out;                      // [7]
  float* Aout = Cout + NCLS;                        // [50000,7]
  float* Bout = Aout + (size_t)NROWS * NCLS;        // [7,1024]

  // 1. dtype converts (+zero padding rows for features)
  k_convert<<<2048, 256, 0, stream>>>(features, Xb, MP, NROWS);
  k_convert<<<128, 256, 0, stream>>>(key_w,   Wk, DDIM, DDIM);
  k_convert<<<128, 256, 0, stream>>>(query_w, Wq, DDIM, DDIM);
  k_convert<<<128, 256, 0, stream>>>(value_w, Wv, DDIM, DDIM);

  // 2. chains: K = chain(X,key) ; V = chain(K,value) ; Q = chain(K,query)
  dim3 gg(8, MP / 128);
  k_gemm_bt<<<gg, 256, 0, stream>>>(Xb, Wk, Hb);
  k_ln_gelu<<<MP / 4, 256, 0, stream>>>(Hb, key_b, key_g, key_beta, Kb);
  k_gemm_bt<<<gg, 256, 0, stream>>>(Kb, Wv, Hb);
  k_ln_gelu<<<MP / 4, 256, 0, stream>>>(Hb, value_b, value_g, value_beta, Vb);
  k_gemm_bt<<<gg, 256, 0, stream>>>(Kb, Wq, Hb);
  k_ln_gelu<<<MP / 4, 256, 0, stream>>>(Hb, query_b, query_g, query_beta, Qb);

  // 3. attention head: q_max = Q[argmax(c)], logits, softmax(axis=0)
  k_argmax<<<1, 256, 0, stream>>>(c_in, top);
  k_logits<<<NROWS / 4, 256, 0, stream>>>(Qb, top, logits);
  k_cmax_part<<<128, 256, 0, stream>>>(logits, Pmax);
  k_cmax_fin<<<1, 32, 0, stream>>>(Pmax, Mmax, 128);
  k_csum_part<<<128, 256, 0, stream>>>(logits, Mmax, Psum);
  k_csum_fin<<<1, 32, 0, stream>>>(Psum, Ssum, 128);
  k_writeA<<<512, 256, 0, stream>>>(logits, Mmax, Ssum, Aout);

  // 4. B = A^T V ; C = head contraction
  dim3 gb(4, 64);
  k_bpart<<<gb, 256, 0, stream>>>(Aout, Vb, Pb);
  k_bred<<<28, 256, 0, stream>>>(Pb, Bout);
  k_head<<<1, 256, 0, stream>>>(Bout, head_w, head_b, Cout);
}

// Round 2
// 829.526 us; speedup vs baseline: 1.1810x; 1.1810x over previous
//
#include <hip/hip_runtime.h>

// ---------------------------------------------------------------------------
// AttDual round 2: XCD-swizzled bf16 MFMA GEMMs, merged V+Q GEMM (N=2048),
// logits fused into Q-LN epilogue vs precomputed q_max, parallel argmax,
// fused A-write into bpart. fp32 in/out, bf16 compute, fp32 accumulate.
// ---------------------------------------------------------------------------

typedef unsigned short u16;
typedef __attribute__((ext_vector_type(8))) short          bf16x8;
typedef __attribute__((ext_vector_type(8))) unsigned short u16x8;
typedef __attribute__((ext_vector_type(4))) unsigned short u16x4;
typedef __attribute__((ext_vector_type(4))) float          f32x4;

#define DDIM  1024
#define NROWS 50000
#define MP    50048      // 391 * 128 padded rows (zeros)
#define NCLS  7
#define MPD4  12512      // MP/4

__device__ __forceinline__ u16 f2bf(float f) {          // RNE fp32 -> bf16
  unsigned u = __float_as_uint(f);
  u = (u + 0x7FFFu + ((u >> 16) & 1u)) >> 16;
  return (u16)u;
}
__device__ __forceinline__ float bf2f(u16 h) {
  return __uint_as_float(((unsigned)h) << 16);
}
__device__ __forceinline__ float gelu(float x) {
  return 0.5f * x * (1.0f + erff(x * 0.70710678118654752f));
}

__device__ __forceinline__ void load16_lds(const u16* g, u16* l) {
  __builtin_amdgcn_global_load_lds(
      (const __attribute__((address_space(1))) unsigned int*)(const void*)g,
      (__attribute__((address_space(3))) unsigned int*)(void*)l, 16, 0, 0);
}

// ------------------------- fp32 -> bf16 convert (features, +row zero-pad) --
__global__ __launch_bounds__(256) void k_convert(const float* __restrict__ src,
                                                 u16* __restrict__ dst,
                                                 int rows_total, int rows_valid) {
  const size_t total = (size_t)rows_total * DDIM / 8;
  const size_t stride = (size_t)gridDim.x * blockDim.x;
  for (size_t i = (size_t)blockIdx.x * blockDim.x + threadIdx.x; i < total; i += stride) {
    const size_t e = i * 8;
    const int row = (int)(e >> 10);
    u16x8 o = {0, 0, 0, 0, 0, 0, 0, 0};
    if (row < rows_valid) {
      const float4* p = (const float4*)(src + e);
      float4 f0 = p[0], f1 = p[1];
      o[0] = f2bf(f0.x); o[1] = f2bf(f0.y); o[2] = f2bf(f0.z); o[3] = f2bf(f0.w);
      o[4] = f2bf(f1.x); o[5] = f2bf(f1.y); o[6] = f2bf(f1.z); o[7] = f2bf(f1.w);
    }
    *(u16x8*)(dst + e) = o;
  }
}

// ------------------------- 3 weight matrices -> Wk, Wvq=concat(Wv,Wq) ------
__global__ __launch_bounds__(256) void k_convw(const float* __restrict__ kw,
                                               const float* __restrict__ vw,
                                               const float* __restrict__ qw,
                                               u16* __restrict__ Wk,
                                               u16* __restrict__ Wvq) {
  const int w = blockIdx.x >> 7;
  const int b = blockIdx.x & 127;
  const float* src = (w == 0) ? kw : (w == 1) ? vw : qw;
  u16* dst = (w == 0) ? Wk : (Wvq + (size_t)(w - 1) * DDIM * DDIM);
  for (int i = b * 256 + threadIdx.x; i < DDIM * DDIM / 8; i += 128 * 256) {
    const float4* p = (const float4*)(src + (size_t)i * 8);
    float4 f0 = p[0], f1 = p[1];
    u16x8 o;
    o[0] = f2bf(f0.x); o[1] = f2bf(f0.y); o[2] = f2bf(f0.z); o[3] = f2bf(f0.w);
    o[4] = f2bf(f1.x); o[5] = f2bf(f1.y); o[6] = f2bf(f1.z); o[7] = f2bf(f1.w);
    *(u16x8*)(dst + (size_t)i * 8) = o;
  }
}

// ------------------------- bf16 GEMM: C[m,n] = sum_k A[m,k]*B[n,k] ---------
// 1-D grid, XCD-bijective swizzle: consecutive virtual ids share an A-panel
// and land on the same XCD's L2. nn = 1<<lnn N-tiles, ldc = nn*128.
__global__ __launch_bounds__(256) void k_gemm_bt(const u16* __restrict__ A,
                                                 const u16* __restrict__ B,
                                                 u16* __restrict__ C,
                                                 int lnn, int ldc) {
  __shared__ __align__(16) u16 As[128 * 32];
  __shared__ __align__(16) u16 Bs[128 * 32];
  const int tid  = threadIdx.x;
  const int lane = tid & 63;
  const int cpx = gridDim.x >> 3;                       // nwg % 8 == 0
  const int v   = (blockIdx.x & 7) * cpx + (blockIdx.x >> 3);
  const int m0 = (v >> lnn) * 128;
  const int n0 = (v & ((1 << lnn) - 1)) * 128;
  const int wid = tid >> 6;
  const int wr = (wid >> 1) * 64;
  const int wc = (wid & 1) * 64;

  const int rA = tid >> 2;
  const int cA = (tid & 3) * 8;
  const u16* Ap0 = A + (size_t)(m0 + rA) * DDIM + cA;
  const u16* Ap1 = Ap0 + (size_t)64 * DDIM;
  const u16* Bp0 = B + (size_t)(n0 + rA) * DDIM + cA;
  const u16* Bp1 = Bp0 + (size_t)64 * DDIM;
  const int wbase = wid * 64;
  u16* AsD0 = &As[(wbase)       * 8];
  u16* AsD1 = &As[(wbase + 256) * 8];
  u16* BsD0 = &Bs[(wbase)       * 8];
  u16* BsD1 = &Bs[(wbase + 256) * 8];

  f32x4 acc[4][4] = {};
  const int fr = lane & 15;
  const int kh = (lane >> 4) * 8;

  for (int k0 = 0; k0 < DDIM; k0 += 32) {
    __syncthreads();
    load16_lds(Ap0 + k0, AsD0);
    load16_lds(Ap1 + k0, AsD1);
    load16_lds(Bp0 + k0, BsD0);
    load16_lds(Bp1 + k0, BsD1);
    __syncthreads();
    bf16x8 a[4], b[4];
#pragma unroll
    for (int i = 0; i < 4; ++i) a[i] = *(const bf16x8*)&As[(wr + i * 16 + fr) * 32 + kh];
#pragma unroll
    for (int j = 0; j < 4; ++j) b[j] = *(const bf16x8*)&Bs[(wc + j * 16 + fr) * 32 + kh];
#pragma unroll
    for (int i = 0; i < 4; ++i)
#pragma unroll
      for (int j = 0; j < 4; ++j)
        acc[i][j] = __builtin_amdgcn_mfma_f32_16x16x32_bf16(a[i], b[j], acc[i][j], 0, 0, 0);
  }

  const int orow = (lane >> 4) * 4;
  const int ocol = lane & 15;
#pragma unroll
  for (int i = 0; i < 4; ++i)
#pragma unroll
    for (int j = 0; j < 4; ++j) {
      const size_t base = (size_t)(m0 + wr + i * 16 + orow) * ldc + (n0 + wc + j * 16 + ocol);
#pragma unroll
      for (int r = 0; r < 4; ++r)
        C[base + (size_t)r * ldc] = f2bf(acc[i][j][r]);
    }
}

// ------------------------- bias + LN + GELU for K (zero-pads rows) ---------
// lane owns cols [lane*8, +8) and [512+lane*8, +8): contiguous 1KB wave loads.
__global__ __launch_bounds__(256) void k_ln_k(const u16* __restrict__ h,
                                              const float* __restrict__ bias,
                                              const float* __restrict__ g,
                                              const float* __restrict__ beta,
                                              u16* __restrict__ out) {
  const int lane = threadIdx.x & 63;
  const int row = blockIdx.x * 4 + (threadIdx.x >> 6);
  const int c0 = lane * 8;
  u16x8* op0 = (u16x8*)(out + (size_t)row * DDIM + c0);
  u16x8* op1 = (u16x8*)(out + (size_t)row * DDIM + 512 + c0);
  if (row >= NROWS) {
    u16x8 z = {0, 0, 0, 0, 0, 0, 0, 0};
    *op0 = z; *op1 = z;
    return;
  }
  u16x8 h0 = *(const u16x8*)(h + (size_t)row * DDIM + c0);
  u16x8 h1 = *(const u16x8*)(h + (size_t)row * DDIM + 512 + c0);
  float4 a0 = *(const float4*)(bias + c0), a1 = *(const float4*)(bias + c0 + 4);
  float4 a2 = *(const float4*)(bias + 512 + c0), a3 = *(const float4*)(bias + 512 + c0 + 4);
  const float ba[8] = {a0.x, a0.y, a0.z, a0.w, a1.x, a1.y, a1.z, a1.w};
  const float bb[8] = {a2.x, a2.y, a2.z, a2.w, a3.x, a3.y, a3.z, a3.w};
  float v0[8], v1[8];
  float s1 = 0.f, s2 = 0.f;
#pragma unroll
  for (int e = 0; e < 8; ++e) {
    v0[e] = bf2f(h0[e]) + ba[e];
    v1[e] = bf2f(h1[e]) + bb[e];
    s1 += v0[e] + v1[e];
    s2 += v0[e] * v0[e] + v1[e] * v1[e];
  }
#pragma unroll
  for (int m = 1; m < 64; m <<= 1) {
    s1 += __shfl_xor(s1, m, 64);
    s2 += __shfl_xor(s2, m, 64);
  }
  const float mu = s1 * (1.0f / 1024.0f);
  const float var = s2 * (1.0f / 1024.0f) - mu * mu;
  const float rs = rsqrtf(var + 1e-5f);
  float4 g0 = *(const float4*)(g + c0), g1 = *(const float4*)(g + c0 + 4);
  float4 g2 = *(const float4*)(g + 512 + c0), g3 = *(const float4*)(g + 512 + c0 + 4);
  float4 t0 = *(const float4*)(beta + c0), t1 = *(const float4*)(beta + c0 + 4);
  float4 t2 = *(const float4*)(beta + 512 + c0), t3 = *(const float4*)(beta + 512 + c0 + 4);
  const float ga[8] = {g0.x, g0.y, g0.z, g0.w, g1.x, g1.y, g1.z, g1.w};
  const float gb[8] = {g2.x, g2.y, g2.z, g2.w, g3.x, g3.y, g3.z, g3.w};
  const float ta[8] = {t0.x, t0.y, t0.z, t0.w, t1.x, t1.y, t1.z, t1.w};
  const float tb[8] = {t2.x, t2.y, t2.z, t2.w, t3.x, t3.y, t3.z, t3.w};
  u16x8 o0, o1;
#pragma unroll
  for (int e = 0; e < 8; ++e) {
    o0[e] = f2bf(gelu((v0[e] - mu) * rs * ga[e] + ta[e]));
    o1[e] = f2bf(gelu((v1[e] - mu) * rs * gb[e] + tb[e]));
  }
  *op0 = o0; *op1 = o1;
}

// ------------------------- q_max[j] = chain(K[top_j], query) ---------------
__global__ __launch_bounds__(256) void k_qmax(const u16* __restrict__ K,
                                              const int* __restrict__ top,
                                              const u16* __restrict__ Wq,
                                              const float* __restrict__ qb,
                                              const float* __restrict__ qg,
                                              const float* __restrict__ qbeta,
                                              u16* __restrict__ qm) {
  __shared__ __align__(16) u16 krow[DDIM];
  __shared__ float w1[4], w2[4];
  const int t = threadIdx.x;
  const int j = blockIdx.x;
  const u16* src = K + (size_t)top[j] * DDIM;
  if (t < 128) *(u16x8*)&krow[t * 8] = *(const u16x8*)&src[t * 8];
  __syncthreads();
  float acc[4];
#pragma unroll
  for (int c = 0; c < 4; ++c) {
    const int col = t * 4 + c;
    const u16x8* wp = (const u16x8*)(Wq + (size_t)col * DDIM);
    float s = 0.f;
    for (int kc = 0; kc < 128; ++kc) {
      u16x8 wv = wp[kc];
      u16x8 kv = *(const u16x8*)&krow[kc * 8];
#pragma unroll
      for (int e = 0; e < 8; ++e) s += bf2f(kv[e]) * bf2f(wv[e]);
    }
    acc[c] = s + qb[col];
  }
  float s1 = acc[0] + acc[1] + acc[2] + acc[3];
  float s2 = acc[0] * acc[0] + acc[1] * acc[1] + acc[2] * acc[2] + acc[3] * acc[3];
#pragma unroll
  for (int m = 1; m < 64; m <<= 1) {
    s1 += __shfl_xor(s1, m, 64);
    s2 += __shfl_xor(s2, m, 64);
  }
  if ((t & 63) == 0) { w1[t >> 6] = s1; w2[t >> 6] = s2; }
  __syncthreads();
  s1 = w1[0] + w1[1] + w1[2] + w1[3];
  s2 = w2[0] + w2[1] + w2[2] + w2[3];
  const float mu = s1 * (1.0f / 1024.0f);
  const float var = s2 * (1.0f / 1024.0f) - mu * mu;
  const float rs = rsqrtf(var + 1e-5f);
#pragma unroll
  for (int c = 0; c < 4; ++c) {
    const int col = t * 4 + c;
    qm[(size_t)j * DDIM + col] = f2bf(gelu((acc[c] - mu) * rs * qg[col] + qbeta[col]));
  }
}

// ------------------------- merged V/Q LN; Q-half emits logits only ---------
// h is [MP,2048]: cols 0..1023 = V-pre, 1024..2047 = Q-pre.
__global__ __launch_bounds__(256) void k_ln_vq(const u16* __restrict__ h,
                                               const float* __restrict__ v_b,
                                               const float* __restrict__ v_g,
                                               const float* __restrict__ v_beta,
                                               const float* __restrict__ q_b,
                                               const float* __restrict__ q_g,
                                               const float* __restrict__ q_beta,
                                               const u16* __restrict__ qm,
                                               u16* __restrict__ V,
                                               float* __restrict__ logits) {
  __shared__ __align__(16) u16 sqm[NCLS * DDIM];        // 14 KB (Q-half only)
  const int tid = threadIdx.x;
  const int lane = tid & 63;
  const int half = (blockIdx.x >= MPD4) ? 1 : 0;
  const int rb = half ? (blockIdx.x - MPD4) : blockIdx.x;
  const int row = rb * 4 + (tid >> 6);
  if (half) {
    for (int i = tid; i < NCLS * DDIM / 8; i += 256)
      *(u16x8*)&sqm[i * 8] = *(const u16x8*)&qm[i * 8];
    __syncthreads();
  }
  if (row >= NROWS) return;                             // no sync after this
  const float* bias = half ? q_b : v_b;
  const float* gain = half ? q_g : v_g;
  const float* bet  = half ? q_beta : v_beta;
  const int c0 = lane * 8;
  const u16* hp = h + (size_t)row * 2048 + (size_t)half * DDIM;
  u16x8 h0 = *(const u16x8*)(hp + c0);
  u16x8 h1 = *(const u16x8*)(hp + 512 + c0);
  float4 a0 = *(const float4*)(bias + c0), a1 = *(const float4*)(bias + c0 + 4);
  float4 a2 = *(const float4*)(bias + 512 + c0), a3 = *(const float4*)(bias + 512 + c0 + 4);
  const float ba[8] = {a0.x, a0.y, a0.z, a0.w, a1.x, a1.y, a1.z, a1.w};
  const float bb[8] = {a2.x, a2.y, a2.z, a2.w, a3.x, a3.y, a3.z, a3.w};
  float v0[8], v1[8];
  float s1 = 0.f, s2 = 0.f;
#pragma unroll
  for (int e = 0; e < 8; ++e) {
    v0[e] = bf2f(h0[e]) + ba[e];
    v1[e] = bf2f(h1[e]) + bb[e];
    s1 += v0[e] + v1[e];
    s2 += v0[e] * v0[e] + v1[e] * v1[e];
  }
#pragma unroll
  for (int m = 1; m < 64; m <<= 1) {
    s1 += __shfl_xor(s1, m, 64);
    s2 += __shfl_xor(s2, m, 64);
  }
  const float mu = s1 * (1.0f / 1024.0f);
  const float var = s2 * (1.0f / 1024.0f) - mu * mu;
  const float rs = rsqrtf(var + 1e-5f);
  float4 g0 = *(const float4*)(gain + c0), g1 = *(const float4*)(gain + c0 + 4);
  float4 g2 = *(const float4*)(gain + 512 + c0), g3 = *(const float4*)(gain + 512 + c0 + 4);
  float4 t0 = *(const float4*)(bet + c0), t1 = *(const float4*)(bet + c0 + 4);
  float4 t2 = *(const float4*)(bet + 512 + c0), t3 = *(const float4*)(bet + 512 + c0 + 4);
  const float ga[8] = {g0.x, g0.y, g0.z, g0.w, g1.x, g1.y, g1.z, g1.w};
  const float gb[8] = {g2.x, g2.y, g2.z, g2.w, g3.x, g3.y, g3.z, g3.w};
  const float ta[8] = {t0.x, t0.y, t0.z, t0.w, t1.x, t1.y, t1.z, t1.w};
  const float tb[8] = {t2.x, t2.y, t2.z, t2.w, t3.x, t3.y, t3.z, t3.w};
  float y0[8], y1[8];
#pragma unroll
  for (int e = 0; e < 8; ++e) {
    y0[e] = gelu((v0[e] - mu) * rs * ga[e] + ta[e]);
    y1[e] = gelu((v1[e] - mu) * rs * gb[e] + tb[e]);
  }
  if (half == 0) {
    u16x8 o0, o1;
#pragma unroll
    for (int e = 0; e < 8; ++e) { o0[e] = f2bf(y0[e]); o1[e] = f2bf(y1[e]); }
    *(u16x8*)(V + (size_t)row * DDIM + c0) = o0;
    *(u16x8*)(V + (size_t)row * DDIM + 512 + c0) = o1;
  } else {
#pragma unroll
    for (int j = 0; j < NCLS; ++j) {
      u16x8 m0 = *(const u16x8*)&sqm[j * DDIM + c0];
      u16x8 m1 = *(const u16x8*)&sqm[j * DDIM + 512 + c0];
      float p = 0.f;
#pragma unroll
      for (int e = 0; e < 8; ++e) p += y0[e] * bf2f(m0[e]) + y1[e] * bf2f(m1[e]);
#pragma unroll
      for (int m = 1; m < 64; m <<= 1) p += __shfl_xor(p, m, 64);
      if (lane == 0) logits[(size_t)row * NCLS + j] = p * 0.03125f;
    }
  }
}

// ------------------------- parallel argmax (first-index), 2 stages ---------
__global__ __launch_bounds__(256) void k_arg1(const float* __restrict__ c,
                                              float* __restrict__ pv,
                                              int* __restrict__ pi) {
  __shared__ float sv[256 * NCLS];
  __shared__ int   si[256 * NCLS];
  const int t = threadIdx.x;
  float bv[NCLS]; int bi[NCLS];
#pragma unroll
  for (int j = 0; j < NCLS; ++j) { bv[j] = -3.4e38f; bi[j] = 0x7fffffff; }
  for (int n = blockIdx.x * 256 + t; n < NROWS; n += 128 * 256) {
#pragma unroll
    for (int j = 0; j < NCLS; ++j) {
      const float v = c[(size_t)n * NCLS + j];
      if (v > bv[j]) { bv[j] = v; bi[j] = n; }          // ascending n in-thread
    }
  }
#pragma unroll
  for (int j = 0; j < NCLS; ++j) { sv[t * NCLS + j] = bv[j]; si[t * NCLS + j] = bi[j]; }
  __syncthreads();
  for (int s = 128; s > 0; s >>= 1) {
    if (t < s) {
#pragma unroll
      for (int j = 0; j < NCLS; ++j) {
        const float v2 = sv[(t + s) * NCLS + j]; const int i2 = si[(t + s) * NCLS + j];
        const float v1 = sv[t * NCLS + j];       const int i1 = si[t * NCLS + j];
        if (v2 > v1 || (v2 == v1 && i2 < i1)) { sv[t * NCLS + j] = v2; si[t * NCLS + j] = i2; }
      }
    }
    __syncthreads();
  }
  if (t < NCLS) { pv[blockIdx.x * NCLS + t] = sv[t]; pi[blockIdx.x * NCLS + t] = si[t]; }
}

__global__ void k_arg2(const float* __restrict__ pv, const int* __restrict__ pi,
                       int* __restrict__ top) {
  __shared__ float sv[128 * NCLS];
  __shared__ int   si[128 * NCLS];
  const int t = threadIdx.x;                           // blockDim = 128
#pragma unroll
  for (int j = 0; j < NCLS; ++j) { sv[t * NCLS + j] = pv[t * NCLS + j]; si[t * NCLS + j] = pi[t * NCLS + j]; }
  __syncthreads();
  for (int s = 64; s > 0; s >>= 1) {
    if (t < s) {
#pragma unroll
      for (int j = 0; j < NCLS; ++j) {
        const float v2 = sv[(t + s) * NCLS + j]; const int i2 = si[(t + s) * NCLS + j];
        const float v1 = sv[t * NCLS + j];       const int i1 = si[t * NCLS + j];
        if (v2 > v1 || (v2 == v1 && i2 < i1)) { sv[t * NCLS + j] = v2; si[t * NCLS + j] = i2; }
      }
    }
    __syncthreads();
  }
  if (t < NCLS) top[t] = si[t];
}

// ------------------------- softmax over axis 0: 2-stage max & sum ----------
__global__ __launch_bounds__(256) void k_cmax_part(const float* __restrict__ logits,
                                                   float* __restrict__ pout) {
  __shared__ float sm[256 * NCLS];
  const int tid = threadIdx.x;
  float m[NCLS];
#pragma unroll
  for (int j = 0; j < NCLS; ++j) m[j] = -3.4e38f;
  const size_t stride = (size_t)gridDim.x * 256;
  for (size_t n = (size_t)blockIdx.x * 256 + tid; n < NROWS; n += stride)
#pragma unroll
    for (int j = 0; j < NCLS; ++j) m[j] = fmaxf(m[j], logits[n * NCLS + j]);
#pragma unroll
  for (int j = 0; j < NCLS; ++j) sm[tid * NCLS + j] = m[j];
  __syncthreads();
  for (int s = 128; s > 0; s >>= 1) {
    if (tid < s)
#pragma unroll
      for (int j = 0; j < NCLS; ++j)
        sm[tid * NCLS + j] = fmaxf(sm[tid * NCLS + j], sm[(tid + s) * NCLS + j]);
    __syncthreads();
  }
  if (tid < NCLS) pout[blockIdx.x * NCLS + tid] = sm[tid];
}

__global__ void k_cmax_fin(const float* __restrict__ pin, float* __restrict__ M, int nparts) {
  const int tid = threadIdx.x;
  if (tid < NCLS) {
    float m = -3.4e38f;
    for (int b = 0; b < nparts; ++b) m = fmaxf(m, pin[b * NCLS + tid]);
    M[tid] = m;
  }
}

__global__ __launch_bounds__(256) void k_csum_part(const float* __restrict__ logits,
                                                   const float* __restrict__ M,
                                                   float* __restrict__ pout) {
  __shared__ float sm[256 * NCLS];
  __shared__ float sM[NCLS];
  const int tid = threadIdx.x;
  if (tid < NCLS) sM[tid] = M[tid];
  __syncthreads();
  float s[NCLS];
#pragma unroll
  for (int j = 0; j < NCLS; ++j) s[j] = 0.f;
  const size_t stride = (size_t)gridDim.x * 256;
  for (size_t n = (size_t)blockIdx.x * 256 + tid; n < NROWS; n += stride)
#pragma unroll
    for (int j = 0; j < NCLS; ++j) s[j] += expf(logits[n * NCLS + j] - sM[j]);
#pragma unroll
  for (int j = 0; j < NCLS; ++j) sm[tid * NCLS + j] = s[j];
  __syncthreads();
  for (int st = 128; st > 0; st >>= 1) {
    if (tid < st)
#pragma unroll
      for (int j = 0; j < NCLS; ++j) sm[tid * NCLS + j] += sm[(tid + st) * NCLS + j];
    __syncthreads();
  }
  if (tid < NCLS) pout[blockIdx.x * NCLS + tid] = sm[tid];
}

__global__ void k_csum_fin(const float* __restrict__ pin, float* __restrict__ S, int nparts) {
  const int tid = threadIdx.x;
  if (tid < NCLS) {
    float s = 0.f;
    for (int b = 0; b < nparts; ++b) s += pin[b * NCLS + tid];
    S[tid] = s;
  }
}

// ------------------------- B-partials = A^T V, fused A-write ---------------
// 512 blocks x 98 rows; thread t owns cols [t*4, t*4+4).
__global__ __launch_bounds__(256) void k_bpart(const float* __restrict__ logits,
                                               const float* __restrict__ M,
                                               const float* __restrict__ S,
                                               const u16* __restrict__ V,
                                               float* __restrict__ Aout,
                                               float* __restrict__ Pb) {
  __shared__ float sA[98 * NCLS];
  __shared__ float sM[NCLS], sR[NCLS];
  const int t = threadIdx.x;
  if (t < NCLS) { sM[t] = M[t]; sR[t] = 1.0f / S[t]; }
  __syncthreads();
  const int n0 = blockIdx.x * 98;
  int cnt = NROWS - n0;
  cnt = cnt < 0 ? 0 : (cnt > 98 ? 98 : cnt);
  for (int idx = t; idx < cnt * NCLS; idx += 256) {
    const int j = idx % NCLS;
    const float a = expf(logits[(size_t)n0 * NCLS + idx] - sM[j]) * sR[j];
    sA[idx] = a;
    Aout[(size_t)n0 * NCLS + idx] = a;
  }
  __syncthreads();
  float acc[NCLS][4] = {};
  for (int r = 0; r < cnt; ++r) {
    u16x4 vv = *(const u16x4*)&V[(size_t)(n0 + r) * DDIM + t * 4];
    const float f0 = bf2f(vv[0]), f1 = bf2f(vv[1]), f2 = bf2f(vv[2]), f3 = bf2f(vv[3]);
#pragma unroll
    for (int j = 0; j < NCLS; ++j) {
      const float a = sA[r * NCLS + j];
      acc[j][0] += a * f0; acc[j][1] += a * f1; acc[j][2] += a * f2; acc[j][3] += a * f3;
    }
  }
#pragma unroll
  for (int j = 0; j < NCLS; ++j) {
    f32x4 o = {acc[j][0], acc[j][1], acc[j][2], acc[j][3]};
    *(f32x4*)&Pb[((size_t)blockIdx.x * NCLS + j) * DDIM + t * 4] = o;
  }
}

__global__ void k_bred(const float* __restrict__ Pb, float* __restrict__ Bout) {
  const int idx = blockIdx.x * 256 + threadIdx.x;
  if (idx >= NCLS * DDIM) return;
  float s = 0.f;
  for (int p = 0; p < 512; ++p) s += Pb[(size_t)p * NCLS * DDIM + idx];
  Bout[idx] = s;
}

// ------------------------- C[o] = <B, head_w[o]> + head_b[o] ---------------
__global__ __launch_bounds__(256) void k_head(const float* __restrict__ Bmat,
                                              const float* __restrict__ hw,
                                              const float* __restrict__ hb,
                                              float* __restrict__ Cout) {
  const int o = blockIdx.x, t = threadIdx.x;
  float p = 0.f;
  for (int idx = t; idx < NCLS * DDIM; idx += 256)
    p += Bmat[idx] * hw[(size_t)o * NCLS * DDIM + idx];
#pragma unroll
  for (int m = 1; m < 64; m <<= 1) p += __shfl_xor(p, m, 64);
  __shared__ float w[4];
  if ((t & 63) == 0) w[t >> 6] = p;
  __syncthreads();
  if (t == 0) Cout[o] = w[0] + w[1] + w[2] + w[3] + hb[o];
}

// ---------------------------------------------------------------------------
extern "C" void kernel_launch(void* const* d_in, const int* in_sizes, int n_in,
                              void* d_out, int out_size, void* d_ws, size_t ws_size,
                              hipStream_t stream) {
  const float* features   = (const float*)d_in[0];
  const float* c_in       = (const float*)d_in[1];
  const float* key_w      = (const float*)d_in[2];
  const float* key_b      = (const float*)d_in[3];
  const float* key_g      = (const float*)d_in[4];
  const float* key_beta   = (const float*)d_in[5];
  const float* query_w    = (const float*)d_in[6];
  const float* query_b    = (const float*)d_in[7];
  const float* query_g    = (const float*)d_in[8];
  const float* query_beta = (const float*)d_in[9];
  const float* value_w    = (const float*)d_in[10];
  const float* value_b    = (const float*)d_in[11];
  const float* value_g    = (const float*)d_in[12];
  const float* value_beta = (const float*)d_in[13];
  const float* head_w     = (const float*)d_in[14];
  const float* head_b     = (const float*)d_in[15];

  char* ws = (char*)d_ws;
  const size_t SZB = (size_t)MP * DDIM * 2;             // 102,498,304 B
  u16* Xb   = (u16*)ws;                                 // [MP,1024]; HbVQ aliases [Xb|HbK]
  u16* HbVQ = Xb;                                       // [MP,2048] after Xb/HbK dead
  u16* HbK  = (u16*)(ws + SZB);
  u16* Kb   = (u16*)(ws + 2 * SZB);
  u16* Vb   = Kb;                                       // reuse after VQ-GEMM consumed Kb
  size_t off = 3 * SZB;
  u16* Wk  = (u16*)(ws + off); off += (size_t)DDIM * DDIM * 2;          // 2 MiB
  u16* Wvq = (u16*)(ws + off); off += (size_t)2 * DDIM * DDIM * 2;      // 4 MiB
  float* logits = (float*)(ws + off); off += ((size_t)NROWS * NCLS * 4 + 255) & ~(size_t)255;
  float* Pb  = (float*)(ws + off); off += (size_t)512 * NCLS * DDIM * 4; // 14.68 MB
  u16* qm    = (u16*)(ws + off); off += ((size_t)NCLS * DDIM * 2 + 255) & ~(size_t)255;
  float* Pmax = (float*)(ws + off); off += ((size_t)128 * NCLS * 4 + 255) & ~(size_t)255;
  float* Psum = (float*)(ws + off); off += ((size_t)128 * NCLS * 4 + 255) & ~(size_t)255;
  float* argv = (float*)(ws + off); off += ((size_t)128 * NCLS * 4 + 255) & ~(size_t)255;
  int*   argi = (int*)  (ws + off); off += ((size_t)128 * NCLS * 4 + 255) & ~(size_t)255;
  float* Mmax = (float*)(ws + off); off += 256;
  float* Ssum = (float*)(ws + off); off += 256;
  int*   top  = (int*)  (ws + off); off += 256;

  float* Cout = (float*)d_out;                          // [7]
  float* Aout = Cout + NCLS;                            // [50000,7]
  float* Bout = Aout + (size_t)NROWS * NCLS;            // [7,1024]

  // argmax of c (independent of everything else) + dtype converts
  k_arg1<<<128, 256, 0, stream>>>(c_in, argv, argi);
  k_arg2<<<1, 128, 0, stream>>>(argv, argi, top);
  k_convert<<<2048, 256, 0, stream>>>(features, Xb, MP, NROWS);
  k_convw<<<384, 256, 0, stream>>>(key_w, value_w, query_w, Wk, Wvq);

  // K chain
  k_gemm_bt<<<3128, 256, 0, stream>>>(Xb, Wk, HbK, 3, 1024);
  k_ln_k<<<MPD4, 256, 0, stream>>>(HbK, key_b, key_g, key_beta, Kb);

  // q_max = chain(K[top], query)  (tiny)
  k_qmax<<<NCLS, 256, 0, stream>>>(Kb, top, Wvq + (size_t)DDIM * DDIM,
                                   query_b, query_g, query_beta, qm);

  // merged V|Q GEMM (N = 2048) + merged LN (V written; Q-half -> logits only)
  k_gemm_bt<<<6256, 256, 0, stream>>>(Kb, Wvq, HbVQ, 4, 2048);
  k_ln_vq<<<2 * MPD4, 256, 0, stream>>>(HbVQ, value_b, value_g, value_beta,
                                        query_b, query_g, query_beta, qm, Vb, logits);

  // softmax over axis 0
  k_cmax_part<<<128, 256, 0, stream>>>(logits, Pmax);
  k_cmax_fin<<<1, 32, 0, stream>>>(Pmax, Mmax, 128);
  k_csum_part<<<128, 256, 0, stream>>>(logits, Mmax, Psum);
  k_csum_fin<<<1, 32, 0, stream>>>(Psum, Ssum, 128);

  // B = A^T V (A materialized on the fly), head contraction
  k_bpart<<<512, 256, 0, stream>>>(logits, Mmax, Ssum, Vb, Aout, Pb);
  k_bred<<<28, 256, 0, stream>>>(Pb, Bout);
  k_head<<<NCLS, 256, 0, stream>>>(Bout, head_w, head_b, Cout);
}

// Round 3
// 823.655 us; speedup vs baseline: 1.1894x; 1.0071x over previous
//
#include <hip/hip_runtime.h>

// ---------------------------------------------------------------------------
// AttDual round 3: 4-buffer LDS ring GEMM with counted vmcnt (never 0 in the
// main loop) + raw s_barrier; q_max taken from HbVQ rows (no dot kernel);
// softmax fin stages folded into consumers. bf16 MFMA, fp32 accumulate.
// ---------------------------------------------------------------------------

typedef unsigned short u16;
typedef __attribute__((ext_vector_type(8))) short          bf16x8;
typedef __attribute__((ext_vector_type(8))) unsigned short u16x8;
typedef __attribute__((ext_vector_type(4))) unsigned short u16x4;
typedef __attribute__((ext_vector_type(4))) float          f32x4;

#define DDIM  1024
#define NROWS 50000
#define MP    50048      // 391 * 128 padded rows (zeros)
#define NCLS  7
#define MPD4  12512      // MP/4

__device__ __forceinline__ u16 f2bf(float f) {          // RNE fp32 -> bf16
  unsigned u = __float_as_uint(f);
  u = (u + 0x7FFFu + ((u >> 16) & 1u)) >> 16;
  return (u16)u;
}
__device__ __forceinline__ float bf2f(u16 h) {
  return __uint_as_float(((unsigned)h) << 16);
}
__device__ __forceinline__ float gelu(float x) {
  return 0.5f * x * (1.0f + erff(x * 0.70710678118654752f));
}

__device__ __forceinline__ void load16_lds(const u16* g, u16* l) {
  __builtin_amdgcn_global_load_lds(
      (const __attribute__((address_space(1))) unsigned int*)(const void*)g,
      (__attribute__((address_space(3))) unsigned int*)(void*)l, 16, 0, 0);
}

// ------------------------- fp32 -> bf16 convert (features, +row zero-pad) --
__global__ __launch_bounds__(256) void k_convert(const float* __restrict__ src,
                                                 u16* __restrict__ dst,
                                                 int rows_total, int rows_valid) {
  const size_t total = (size_t)rows_total * DDIM / 8;
  const size_t stride = (size_t)gridDim.x * blockDim.x;
  for (size_t i = (size_t)blockIdx.x * blockDim.x + threadIdx.x; i < total; i += stride) {
    const size_t e = i * 8;
    const int row = (int)(e >> 10);
    u16x8 o = {0, 0, 0, 0, 0, 0, 0, 0};
    if (row < rows_valid) {
      const float4* p = (const float4*)(src + e);
      float4 f0 = p[0], f1 = p[1];
      o[0] = f2bf(f0.x); o[1] = f2bf(f0.y); o[2] = f2bf(f0.z); o[3] = f2bf(f0.w);
      o[4] = f2bf(f1.x); o[5] = f2bf(f1.y); o[6] = f2bf(f1.z); o[7] = f2bf(f1.w);
    }
    *(u16x8*)(dst + e) = o;
  }
}

// ------------------------- 3 weight matrices -> Wk, Wvq=concat(Wv,Wq) ------
__global__ __launch_bounds__(256) void k_convw(const float* __restrict__ kw,
                                               const float* __restrict__ vw,
                                               const float* __restrict__ qw,
                                               u16* __restrict__ Wk,
                                               u16* __restrict__ Wvq) {
  const int w = blockIdx.x >> 7;
  const int b = blockIdx.x & 127;
  const float* src = (w == 0) ? kw : (w == 1) ? vw : qw;
  u16* dst = (w == 0) ? Wk : (Wvq + (size_t)(w - 1) * DDIM * DDIM);
  for (int i = b * 256 + threadIdx.x; i < DDIM * DDIM / 8; i += 128 * 256) {
    const float4* p = (const float4*)(src + (size_t)i * 8);
    float4 f0 = p[0], f1 = p[1];
    u16x8 o;
    o[0] = f2bf(f0.x); o[1] = f2bf(f0.y); o[2] = f2bf(f0.z); o[3] = f2bf(f0.w);
    o[4] = f2bf(f1.x); o[5] = f2bf(f1.y); o[6] = f2bf(f1.z); o[7] = f2bf(f1.w);
    *(u16x8*)(dst + (size_t)i * 8) = o;
  }
}

// ------------------------- bf16 GEMM: C[m,n] = sum_k A[m,k]*B[n,k] ---------
// 128x128 tile, BK=32, 4 waves, 4-buffer LDS ring with counted vmcnt:
// stage kt+3 into the buffer that died at end of iter kt-1 (race-free),
// drain only the oldest in-flight K-tile per barrier (vmcnt(8), never 0).
__global__ __launch_bounds__(256) void k_gemm_bt(const u16* __restrict__ A,
                                                 const u16* __restrict__ B,
                                                 u16* __restrict__ C,
                                                 int lnn, int ldc) {
  __shared__ __align__(16) u16 As[4][4096];   // [buf][128*32] = 32 KB
  __shared__ __align__(16) u16 Bs[4][4096];   // 32 KB
  const int tid  = threadIdx.x;
  const int lane = tid & 63;
  const int cpx = gridDim.x >> 3;                       // nwg % 8 == 0
  const int v   = (blockIdx.x & 7) * cpx + (blockIdx.x >> 3);
  const int m0 = (v >> lnn) * 128;
  const int n0 = (v & ((1 << lnn) - 1)) * 128;
  const int wid = tid >> 6;
  const int wr = (wid >> 1) * 64;
  const int wc = (wid & 1) * 64;

  const int rA = tid >> 2;                              // 0..63
  const int cA = (tid & 3) * 8;
  const u16* Ap0 = A + (size_t)(m0 + rA) * DDIM + cA;
  const u16* Ap1 = Ap0 + (size_t)64 * DDIM;
  const u16* Bp0 = B + (size_t)(n0 + rA) * DDIM + cA;
  const u16* Bp1 = Bp0 + (size_t)64 * DDIM;
  const int wb8 = wid * 512;                            // wave-uniform LDS chunk

  f32x4 acc[4][4] = {};
  const int fr = lane & 15;
  const int kh = (lane >> 4) * 8;

#define STAGE_KT(KT) do { const int _b = (KT) & 3; const int _ko = (KT) * 32;  \
    load16_lds(Ap0 + _ko, &As[_b][wb8]);                                       \
    load16_lds(Ap1 + _ko, &As[_b][wb8 + 2048]);                                \
    load16_lds(Bp0 + _ko, &Bs[_b][wb8]);                                       \
    load16_lds(Bp1 + _ko, &Bs[_b][wb8 + 2048]); } while (0)

#define COMPUTE_KT(KT) do { const int _b = (KT) & 3;                           \
    const u16* _Ab = &As[_b][0]; const u16* _Bb = &Bs[_b][0];                  \
    bf16x8 a[4], b[4];                                                         \
    _Pragma("unroll") for (int i = 0; i < 4; ++i)                              \
      a[i] = *(const bf16x8*)&_Ab[(wr + i * 16 + fr) * 32 + kh];               \
    _Pragma("unroll") for (int j = 0; j < 4; ++j)                              \
      b[j] = *(const bf16x8*)&_Bb[(wc + j * 16 + fr) * 32 + kh];               \
    _Pragma("unroll") for (int i = 0; i < 4; ++i)                              \
      _Pragma("unroll") for (int j = 0; j < 4; ++j)                            \
        acc[i][j] = __builtin_amdgcn_mfma_f32_16x16x32_bf16(a[i], b[j],        \
                                                            acc[i][j], 0, 0, 0); } while (0)

  // prologue: fill 3 buffers; wait until kt0 landed (8 newest loads in flight)
  STAGE_KT(0); STAGE_KT(1); STAGE_KT(2);
  asm volatile("s_waitcnt vmcnt(8)\n\ts_barrier" ::: "memory");

#pragma unroll 4
  for (int kt = 0; kt < 28; ++kt) {
    STAGE_KT(kt + 3);                // into buffer (kt-1)&3, dead since last iter
    COMPUTE_KT(kt);
    // 12 loads in flight (kt+1..kt+3); drain kt+1's four, keep 8 flying
    asm volatile("s_waitcnt vmcnt(8)\n\ts_barrier" ::: "memory");
  }
  STAGE_KT(31);
  COMPUTE_KT(28);
  asm volatile("s_waitcnt vmcnt(8)\n\ts_barrier" ::: "memory");
  COMPUTE_KT(29);
  asm volatile("s_waitcnt vmcnt(4)\n\ts_barrier" ::: "memory");
  COMPUTE_KT(30);
  asm volatile("s_waitcnt vmcnt(0)\n\ts_barrier" ::: "memory");
  COMPUTE_KT(31);
#undef STAGE_KT
#undef COMPUTE_KT

  const int orow = (lane >> 4) * 4;
  const int ocol = lane & 15;
#pragma unroll
  for (int i = 0; i < 4; ++i)
#pragma unroll
    for (int j = 0; j < 4; ++j) {
      const size_t base = (size_t)(m0 + wr + i * 16 + orow) * ldc + (n0 + wc + j * 16 + ocol);
#pragma unroll
      for (int r = 0; r < 4; ++r)
        C[base + (size_t)r * ldc] = f2bf(acc[i][j][r]);
    }
}

// ------------------------- bias + LN + GELU for K (zero-pads rows) ---------
__global__ __launch_bounds__(256) void k_ln_k(const u16* __restrict__ h,
                                              const float* __restrict__ bias,
                                              const float* __restrict__ g,
                                              const float* __restrict__ beta,
                                              u16* __restrict__ out) {
  const int lane = threadIdx.x & 63;
  const int row = blockIdx.x * 4 + (threadIdx.x >> 6);
  const int c0 = lane * 8;
  u16x8* op0 = (u16x8*)(out + (size_t)row * DDIM + c0);
  u16x8* op1 = (u16x8*)(out + (size_t)row * DDIM + 512 + c0);
  if (row >= NROWS) {
    u16x8 z = {0, 0, 0, 0, 0, 0, 0, 0};
    *op0 = z; *op1 = z;
    return;
  }
  u16x8 h0 = *(const u16x8*)(h + (size_t)row * DDIM + c0);
  u16x8 h1 = *(const u16x8*)(h + (size_t)row * DDIM + 512 + c0);
  float4 a0 = *(const float4*)(bias + c0), a1 = *(const float4*)(bias + c0 + 4);
  float4 a2 = *(const float4*)(bias + 512 + c0), a3 = *(const float4*)(bias + 512 + c0 + 4);
  const float ba[8] = {a0.x, a0.y, a0.z, a0.w, a1.x, a1.y, a1.z, a1.w};
  const float bb[8] = {a2.x, a2.y, a2.z, a2.w, a3.x, a3.y, a3.z, a3.w};
  float v0[8], v1[8];
  float s1 = 0.f, s2 = 0.f;
#pragma unroll
  for (int e = 0; e < 8; ++e) {
    v0[e] = bf2f(h0[e]) + ba[e];
    v1[e] = bf2f(h1[e]) + bb[e];
    s1 += v0[e] + v1[e];
    s2 += v0[e] * v0[e] + v1[e] * v1[e];
  }
#pragma unroll
  for (int m = 1; m < 64; m <<= 1) {
    s1 += __shfl_xor(s1, m, 64);
    s2 += __shfl_xor(s2, m, 64);
  }
  const float mu = s1 * (1.0f / 1024.0f);
  const float var = s2 * (1.0f / 1024.0f) - mu * mu;
  const float rs = rsqrtf(var + 1e-5f);
  float4 g0 = *(const float4*)(g + c0), g1 = *(const float4*)(g + c0 + 4);
  float4 g2 = *(const float4*)(g + 512 + c0), g3 = *(const float4*)(g + 512 + c0 + 4);
  float4 t0 = *(const float4*)(beta + c0), t1 = *(const float4*)(beta + c0 + 4);
  float4 t2 = *(const float4*)(beta + 512 + c0), t3 = *(const float4*)(beta + 512 + c0 + 4);
  const float ga[8] = {g0.x, g0.y, g0.z, g0.w, g1.x, g1.y, g1.z, g1.w};
  const float gb[8] = {g2.x, g2.y, g2.z, g2.w, g3.x, g3.y, g3.z, g3.w};
  const float ta[8] = {t0.x, t0.y, t0.z, t0.w, t1.x, t1.y, t1.z, t1.w};
  const float tb[8] = {t2.x, t2.y, t2.z, t2.w, t3.x, t3.y, t3.z, t3.w};
  u16x8 o0, o1;
#pragma unroll
  for (int e = 0; e < 8; ++e) {
    o0[e] = f2bf(gelu((v0[e] - mu) * rs * ga[e] + ta[e]));
    o1[e] = f2bf(gelu((v1[e] - mu) * rs * gb[e] + tb[e]));
  }
  *op0 = o0; *op1 = o1;
}

// ------------------------- q_max from HbVQ rows (post-GEMM) ----------------
// block j: fin the argmax partials -> row, then bias+LN+GELU of Hq[row].
__global__ __launch_bounds__(64) void k_qmax2(const float* __restrict__ argv,
                                              const int* __restrict__ argi,
                                              const u16* __restrict__ hvq,
                                              const float* __restrict__ qb,
                                              const float* __restrict__ qg,
                                              const float* __restrict__ qbeta,
                                              u16* __restrict__ qm) {
  const int j = blockIdx.x;
  const int lane = threadIdx.x;
  float bv = -3.4e38f; int bi = 0x7fffffff;
  for (int p = lane; p < 128; p += 64) {
    const float v = argv[p * NCLS + j];
    const int   i = argi[p * NCLS + j];
    if (v > bv || (v == bv && i < bi)) { bv = v; bi = i; }
  }
#pragma unroll
  for (int m = 1; m < 64; m <<= 1) {
    const float ov = __shfl_xor(bv, m, 64);
    const int   oi = __shfl_xor(bi, m, 64);
    if (ov > bv || (ov == bv && oi < bi)) { bv = ov; bi = oi; }
  }
  const int row = bi;
  const int c0 = lane * 8;
  const u16* hp = hvq + (size_t)row * 2048 + DDIM;      // Q-half
  u16x8 h0 = *(const u16x8*)(hp + c0);
  u16x8 h1 = *(const u16x8*)(hp + 512 + c0);
  float v0[8], v1[8];
  float s1 = 0.f, s2 = 0.f;
#pragma unroll
  for (int e = 0; e < 8; ++e) {
    v0[e] = bf2f(h0[e]) + qb[c0 + e];
    v1[e] = bf2f(h1[e]) + qb[512 + c0 + e];
    s1 += v0[e] + v1[e];
    s2 += v0[e] * v0[e] + v1[e] * v1[e];
  }
#pragma unroll
  for (int m = 1; m < 64; m <<= 1) {
    s1 += __shfl_xor(s1, m, 64);
    s2 += __shfl_xor(s2, m, 64);
  }
  const float mu = s1 * (1.0f / 1024.0f);
  const float var = s2 * (1.0f / 1024.0f) - mu * mu;
  const float rs = rsqrtf(var + 1e-5f);
  u16x8 o0, o1;
#pragma unroll
  for (int e = 0; e < 8; ++e) {
    o0[e] = f2bf(gelu((v0[e] - mu) * rs * qg[c0 + e] + qbeta[c0 + e]));
    o1[e] = f2bf(gelu((v1[e] - mu) * rs * qg[512 + c0 + e] + qbeta[512 + c0 + e]));
  }
  *(u16x8*)(qm + (size_t)j * DDIM + c0) = o0;
  *(u16x8*)(qm + (size_t)j * DDIM + 512 + c0) = o1;
}

// ------------------------- merged V/Q LN; Q-half emits logits only ---------
__global__ __launch_bounds__(256) void k_ln_vq(const u16* __restrict__ h,
                                               const float* __restrict__ v_b,
                                               const float* __restrict__ v_g,
                                               const float* __restrict__ v_beta,
                                               const float* __restrict__ q_b,
                                               const float* __restrict__ q_g,
                                               const float* __restrict__ q_beta,
                                               const u16* __restrict__ qm,
                                               u16* __restrict__ V,
                                               float* __restrict__ logits) {
  __shared__ __align__(16) u16 sqm[NCLS * DDIM];        // 14 KB
  const int tid = threadIdx.x;
  const int lane = tid & 63;
  const int half = (blockIdx.x >= MPD4) ? 1 : 0;
  const int rb = half ? (blockIdx.x - MPD4) : blockIdx.x;
  const int row = rb * 4 + (tid >> 6);
  if (half) {
    for (int i = tid; i < NCLS * DDIM / 8; i += 256)
      *(u16x8*)&sqm[i * 8] = *(const u16x8*)&qm[i * 8];
    __syncthreads();
  }
  if (row >= NROWS) return;                             // no sync after this
  const float* bias = half ? q_b : v_b;
  const float* gain = half ? q_g : v_g;
  const float* bet  = half ? q_beta : v_beta;
  const int c0 = lane * 8;
  const u16* hp = h + (size_t)row * 2048 + (size_t)half * DDIM;
  u16x8 h0 = *(const u16x8*)(hp + c0);
  u16x8 h1 = *(const u16x8*)(hp + 512 + c0);
  float4 a0 = *(const float4*)(bias + c0), a1 = *(const float4*)(bias + c0 + 4);
  float4 a2 = *(const float4*)(bias + 512 + c0), a3 = *(const float4*)(bias + 512 + c0 + 4);
  const float ba[8] = {a0.x, a0.y, a0.z, a0.w, a1.x, a1.y, a1.z, a1.w};
  const float bb[8] = {a2.x, a2.y, a2.z, a2.w, a3.x, a3.y, a3.z, a3.w};
  float v0[8], v1[8];
  float s1 = 0.f, s2 = 0.f;
#pragma unroll
  for (int e = 0; e < 8; ++e) {
    v0[e] = bf2f(h0[e]) + ba[e];
    v1[e] = bf2f(h1[e]) + bb[e];
    s1 += v0[e] + v1[e];
    s2 += v0[e] * v0[e] + v1[e] * v1[e];
  }
#pragma unroll
  for (int m = 1; m < 64; m <<= 1) {
    s1 += __shfl_xor(s1, m, 64);
    s2 += __shfl_xor(s2, m, 64);
  }
  const float mu = s1 * (1.0f / 1024.0f);
  const float var = s2 * (1.0f / 1024.0f) - mu * mu;
  const float rs = rsqrtf(var + 1e-5f);
  float4 g0 = *(const float4*)(gain + c0), g1 = *(const float4*)(gain + c0 + 4);
  float4 g2 = *(const float4*)(gain + 512 + c0), g3 = *(const float4*)(gain + 512 + c0 + 4);
  float4 t0 = *(const float4*)(bet + c0), t1 = *(const float4*)(bet + c0 + 4);
  float4 t2 = *(const float4*)(bet + 512 + c0), t3 = *(const float4*)(bet + 512 + c0 + 4);
  const float ga[8] = {g0.x, g0.y, g0.z, g0.w, g1.x, g1.y, g1.z, g1.w};
  const float gb[8] = {g2.x, g2.y, g2.z, g2.w, g3.x, g3.y, g3.z, g3.w};
  const float ta[8] = {t0.x, t0.y, t0.z, t0.w, t1.x, t1.y, t1.z, t1.w};
  const float tb[8] = {t2.x, t2.y, t2.z, t2.w, t3.x, t3.y, t3.z, t3.w};
  float y0[8], y1[8];
#pragma unroll
  for (int e = 0; e < 8; ++e) {
    y0[e] = gelu((v0[e] - mu) * rs * ga[e] + ta[e]);
    y1[e] = gelu((v1[e] - mu) * rs * gb[e] + tb[e]);
  }
  if (half == 0) {
    u16x8 o0, o1;
#pragma unroll
    for (int e = 0; e < 8; ++e) { o0[e] = f2bf(y0[e]); o1[e] = f2bf(y1[e]); }
    *(u16x8*)(V + (size_t)row * DDIM + c0) = o0;
    *(u16x8*)(V + (size_t)row * DDIM + 512 + c0) = o1;
  } else {
#pragma unroll
    for (int j = 0; j < NCLS; ++j) {
      u16x8 m0 = *(const u16x8*)&sqm[j * DDIM + c0];
      u16x8 m1 = *(const u16x8*)&sqm[j * DDIM + 512 + c0];
      float p = 0.f;
#pragma unroll
      for (int e = 0; e < 8; ++e) p += y0[e] * bf2f(m0[e]) + y1[e] * bf2f(m1[e]);
#pragma unroll
      for (int m = 1; m < 64; m <<= 1) p += __shfl_xor(p, m, 64);
      if (lane == 0) logits[(size_t)row * NCLS + j] = p * 0.03125f;
    }
  }
}

// ------------------------- argmax partials (first-index) -------------------
__global__ __launch_bounds__(256) void k_arg1(const float* __restrict__ c,
                                              float* __restrict__ pv,
                                              int* __restrict__ pi) {
  __shared__ float sv[256 * NCLS];
  __shared__ int   si[256 * NCLS];
  const int t = threadIdx.x;
  float bv[NCLS]; int bi[NCLS];
#pragma unroll
  for (int j = 0; j < NCLS; ++j) { bv[j] = -3.4e38f; bi[j] = 0x7fffffff; }
  for (int n = blockIdx.x * 256 + t; n < NROWS; n += 128 * 256) {
#pragma unroll
    for (int j = 0; j < NCLS; ++j) {
      const float v = c[(size_t)n * NCLS + j];
      if (v > bv[j]) { bv[j] = v; bi[j] = n; }
    }
  }
#pragma unroll
  for (int j = 0; j < NCLS; ++j) { sv[t * NCLS + j] = bv[j]; si[t * NCLS + j] = bi[j]; }
  __syncthreads();
  for (int s = 128; s > 0; s >>= 1) {
    if (t < s) {
#pragma unroll
      for (int j = 0; j < NCLS; ++j) {
        const float v2 = sv[(t + s) * NCLS + j]; const int i2 = si[(t + s) * NCLS + j];
        const float v1 = sv[t * NCLS + j];       const int i1 = si[t * NCLS + j];
        if (v2 > v1 || (v2 == v1 && i2 < i1)) { sv[t * NCLS + j] = v2; si[t * NCLS + j] = i2; }
      }
    }
    __syncthreads();
  }
  if (t < NCLS) { pv[blockIdx.x * NCLS + t] = sv[t]; pi[blockIdx.x * NCLS + t] = si[t]; }
}

// ------------------------- softmax over axis 0 -----------------------------
__global__ __launch_bounds__(256) void k_cmax_part(const float* __restrict__ logits,
                                                   float* __restrict__ pout) {
  __shared__ float sm[256 * NCLS];
  const int tid = threadIdx.x;
  float m[NCLS];
#pragma unroll
  for (int j = 0; j < NCLS; ++j) m[j] = -3.4e38f;
  const size_t stride = (size_t)gridDim.x * 256;
  for (size_t n = (size_t)blockIdx.x * 256 + tid; n < NROWS; n += stride)
#pragma unroll
    for (int j = 0; j < NCLS; ++j) m[j] = fmaxf(m[j], logits[n * NCLS + j]);
#pragma unroll
  for (int j = 0; j < NCLS; ++j) sm[tid * NCLS + j] = m[j];
  __syncthreads();
  for (int s = 128; s > 0; s >>= 1) {
    if (tid < s)
#pragma unroll
      for (int j = 0; j < NCLS; ++j)
        sm[tid * NCLS + j] = fmaxf(sm[tid * NCLS + j], sm[(tid + s) * NCLS + j]);
    __syncthreads();
  }
  if (tid < NCLS) pout[blockIdx.x * NCLS + tid] = sm[tid];
}

// csum_part also does the max-fin per block (deterministic serial order).
__global__ __launch_bounds__(256) void k_csum_part(const float* __restrict__ logits,
                                                   const float* __restrict__ Pmax,
                                                   float* __restrict__ pout) {
  __shared__ float sm[256 * NCLS];
  __shared__ float sM[NCLS];
  const int tid = threadIdx.x;
  if (tid < NCLS) {
    float m = -3.4e38f;
    for (int b = 0; b < 128; ++b) m = fmaxf(m, Pmax[b * NCLS + tid]);
    sM[tid] = m;
  }
  __syncthreads();
  float s[NCLS];
#pragma unroll
  for (int j = 0; j < NCLS; ++j) s[j] = 0.f;
  const size_t stride = (size_t)gridDim.x * 256;
  for (size_t n = (size_t)blockIdx.x * 256 + tid; n < NROWS; n += stride)
#pragma unroll
    for (int j = 0; j < NCLS; ++j) s[j] += expf(logits[n * NCLS + j] - sM[j]);
#pragma unroll
  for (int j = 0; j < NCLS; ++j) sm[tid * NCLS + j] = s[j];
  __syncthreads();
  for (int st = 128; st > 0; st >>= 1) {
    if (tid < st)
#pragma unroll
      for (int j = 0; j < NCLS; ++j) sm[tid * NCLS + j] += sm[(tid + st) * NCLS + j];
    __syncthreads();
  }
  if (tid < NCLS) pout[blockIdx.x * NCLS + tid] = sm[tid];
}

// ------------------------- B-partials = A^T V, fused A-write + sum-fin -----
__global__ __launch_bounds__(256) void k_bpart(const float* __restrict__ logits,
                                               const float* __restrict__ Pmax,
                                               const float* __restrict__ Psum,
                                               const u16* __restrict__ V,
                                               float* __restrict__ Aout,
                                               float* __restrict__ Pb) {
  __shared__ float sA[98 * NCLS];
  __shared__ float sM[NCLS], sR[NCLS];
  const int t = threadIdx.x;
  if (t < NCLS) {
    float m = -3.4e38f;
    for (int b = 0; b < 128; ++b) m = fmaxf(m, Pmax[b * NCLS + t]);   // same order
    float s = 0.f;
    for (int b = 0; b < 128; ++b) s += Psum[b * NCLS + t];
    sM[t] = m; sR[t] = 1.0f / s;
  }
  __syncthreads();
  const int n0 = blockIdx.x * 98;
  int cnt = NROWS - n0;
  cnt = cnt < 0 ? 0 : (cnt > 98 ? 98 : cnt);
  for (int idx = t; idx < cnt * NCLS; idx += 256) {
    const int j = idx % NCLS;
    const float a = expf(logits[(size_t)n0 * NCLS + idx] - sM[j]) * sR[j];
    sA[idx] = a;
    Aout[(size_t)n0 * NCLS + idx] = a;
  }
  __syncthreads();
  float acc[NCLS][4] = {};
  for (int r = 0; r < cnt; ++r) {
    u16x4 vv = *(const u16x4*)&V[(size_t)(n0 + r) * DDIM + t * 4];
    const float f0 = bf2f(vv[0]), f1 = bf2f(vv[1]), f2 = bf2f(vv[2]), f3 = bf2f(vv[3]);
#pragma unroll
    for (int j = 0; j < NCLS; ++j) {
      const float a = sA[r * NCLS + j];
      acc[j][0] += a * f0; acc[j][1] += a * f1; acc[j][2] += a * f2; acc[j][3] += a * f3;
    }
  }
#pragma unroll
  for (int j = 0; j < NCLS; ++j) {
    f32x4 o = {acc[j][0], acc[j][1], acc[j][2], acc[j][3]};
    *(f32x4*)&Pb[((size_t)blockIdx.x * NCLS + j) * DDIM + t * 4] = o;
  }
}

__global__ void k_bred(const float* __restrict__ Pb, float* __restrict__ Bout) {
  const int idx = blockIdx.x * 256 + threadIdx.x;
  if (idx >= NCLS * DDIM) return;
  float s = 0.f;
  for (int p = 0; p < 512; ++p) s += Pb[(size_t)p * NCLS * DDIM + idx];
  Bout[idx] = s;
}

// ------------------------- C[o] = <B, head_w[o]> + head_b[o] ---------------
__global__ __launch_bounds__(256) void k_head(const float* __restrict__ Bmat,
                                              const float* __restrict__ hw,
                                              const float* __restrict__ hb,
                                              float* __restrict__ Cout) {
  const int o = blockIdx.x, t = threadIdx.x;
  float p = 0.f;
  for (int idx = t; idx < NCLS * DDIM; idx += 256)
    p += Bmat[idx] * hw[(size_t)o * NCLS * DDIM + idx];
#pragma unroll
  for (int m = 1; m < 64; m <<= 1) p += __shfl_xor(p, m, 64);
  __shared__ float w[4];
  if ((t & 63) == 0) w[t >> 6] = p;
  __syncthreads();
  if (t == 0) Cout[o] = w[0] + w[1] + w[2] + w[3] + hb[o];
}

// ---------------------------------------------------------------------------
extern "C" void kernel_launch(void* const* d_in, const int* in_sizes, int n_in,
                              void* d_out, int out_size, void* d_ws, size_t ws_size,
                              hipStream_t stream) {
  const float* features   = (const float*)d_in[0];
  const float* c_in       = (const float*)d_in[1];
  const float* key_w      = (const float*)d_in[2];
  const float* key_b      = (const float*)d_in[3];
  const float* key_g      = (const float*)d_in[4];
  const float* key_beta   = (const float*)d_in[5];
  const float* query_w    = (const float*)d_in[6];
  const float* query_b    = (const float*)d_in[7];
  const float* query_g    = (const float*)d_in[8];
  const float* query_beta = (const float*)d_in[9];
  const float* value_w    = (const float*)d_in[10];
  const float* value_b    = (const float*)d_in[11];
  const float* value_g    = (const float*)d_in[12];
  const float* value_beta = (const float*)d_in[13];
  const float* head_w     = (const float*)d_in[14];
  const float* head_b     = (const float*)d_in[15];

  char* ws = (char*)d_ws;
  const size_t SZB = (size_t)MP * DDIM * 2;             // 102,498,304 B
  u16* Xb   = (u16*)ws;                                 // [MP,1024]
  u16* HbVQ = Xb;                                       // [MP,2048] aliases Xb|HbK
  u16* HbK  = (u16*)(ws + SZB);
  u16* Kb   = (u16*)(ws + 2 * SZB);
  u16* Vb   = Kb;                                       // reuse after VQ-GEMM
  size_t off = 3 * SZB;
  u16* Wk  = (u16*)(ws + off); off += (size_t)DDIM * DDIM * 2;
  u16* Wvq = (u16*)(ws + off); off += (size_t)2 * DDIM * DDIM * 2;
  float* logits = (float*)(ws + off); off += ((size_t)NROWS * NCLS * 4 + 255) & ~(size_t)255;
  float* Pb  = (float*)(ws + off); off += (size_t)512 * NCLS * DDIM * 4;
  u16* qm    = (u16*)(ws + off); off += ((size_t)NCLS * DDIM * 2 + 255) & ~(size_t)255;
  float* Pmax = (float*)(ws + off); off += ((size_t)128 * NCLS * 4 + 255) & ~(size_t)255;
  float* Psum = (float*)(ws + off); off += ((size_t)128 * NCLS * 4 + 255) & ~(size_t)255;
  float* argv = (float*)(ws + off); off += ((size_t)128 * NCLS * 4 + 255) & ~(size_t)255;
  int*   argi = (int*)  (ws + off); off += ((size_t)128 * NCLS * 4 + 255) & ~(size_t)255;

  float* Cout = (float*)d_out;                          // [7]
  float* Aout = Cout + NCLS;                            // [50000,7]
  float* Bout = Aout + (size_t)NROWS * NCLS;            // [7,1024]

  // argmax partials + dtype converts
  k_arg1<<<128, 256, 0, stream>>>(c_in, argv, argi);
  k_convert<<<2048, 256, 0, stream>>>(features, Xb, MP, NROWS);
  k_convw<<<384, 256, 0, stream>>>(key_w, value_w, query_w, Wk, Wvq);

  // K chain
  k_gemm_bt<<<3128, 256, 0, stream>>>(Xb, Wk, HbK, 3, 1024);
  k_ln_k<<<MPD4, 256, 0, stream>>>(HbK, key_b, key_g, key_beta, Kb);

  // merged V|Q GEMM, then q_max from HbVQ, then merged LN (V + logits)
  k_gemm_bt<<<6256, 256, 0, stream>>>(Kb, Wvq, HbVQ, 4, 2048);
  k_qmax2<<<NCLS, 64, 0, stream>>>(argv, argi, HbVQ, query_b, query_g, query_beta, qm);
  k_ln_vq<<<2 * MPD4, 256, 0, stream>>>(HbVQ, value_b, value_g, value_beta,
                                        query_b, query_g, query_beta, qm, Vb, logits);

  // softmax over axis 0 (fin stages folded into consumers)
  k_cmax_part<<<128, 256, 0, stream>>>(logits, Pmax);
  k_csum_part<<<128, 256, 0, stream>>>(logits, Pmax, Psum);

  // B = A^T V (A materialized on the fly), head contraction
  k_bpart<<<512, 256, 0, stream>>>(logits, Pmax, Psum, Vb, Aout, Pb);
  k_bred<<<28, 256, 0, stream>>>(Pb, Bout);
  k_head<<<NCLS, 256, 0, stream>>>(Bout, head_w, head_b, Cout);
}